// Round 1
// baseline (560.069 us; speedup 1.0000x reference)
//
#include <hip/hip_runtime.h>
#include <math.h>

// ---------------------------------------------------------------------------
// NeuralNet_62045097558546: 3x (GEMM+bias+ReLU -> soft-topk mask) -> GEMM+bias
// M=4096, d_in=1024, d_h=500, d_out=10, K(topk)=400, eps=0.1, 50 Sinkhorn iters
// ---------------------------------------------------------------------------

#define TILE_K 16

__global__ __launch_bounds__(256) void gemm_bias_relu(
    const float* __restrict__ A, const float* __restrict__ B,
    const float* __restrict__ bias, float* __restrict__ C,
    int M, int N, int K)
{
  // 64x64 block tile, 256 threads, 4x4 per thread. M must be multiple of 64.
  __shared__ float As[TILE_K][64 + 4];
  __shared__ float Bs[TILE_K][64 + 4];
  const int tid  = threadIdx.x;
  const int row0 = blockIdx.y * 64;
  const int col0 = blockIdx.x * 64;
  const int tx = tid & 15;
  const int ty = tid >> 4;
  float acc[4][4] = {};

  for (int k0 = 0; k0 < K; k0 += TILE_K) {
    // ---- load A tile: 64 rows x 16 k (each thread 4 elements) ----
    {
      const int ak = tid & 15;
      const int base_r = tid >> 4;
      #pragma unroll
      for (int r = 0; r < 4; ++r) {
        const int arow = base_r + r * 16;
        const int kk = k0 + ak;
        float v = 0.0f;
        if (kk < K) v = A[(size_t)(row0 + arow) * K + kk];
        As[ak][arow] = v;
      }
    }
    // ---- load B tile: 16 k x 64 cols ----
    {
      const int bcol = tid & 63;
      const int base_k = tid >> 6;
      #pragma unroll
      for (int r = 0; r < 4; ++r) {
        const int bk = base_k + r * 4;
        const int kk = k0 + bk;
        const int c = col0 + bcol;
        float v = 0.0f;
        if (kk < K && c < N) v = B[(size_t)kk * N + c];
        Bs[bk][bcol] = v;
      }
    }
    __syncthreads();

    #pragma unroll
    for (int kk = 0; kk < TILE_K; ++kk) {
      const float4 av = *reinterpret_cast<const float4*>(&As[kk][ty * 4]);
      const float4 bv = *reinterpret_cast<const float4*>(&Bs[kk][tx * 4]);
      const float a_[4] = {av.x, av.y, av.z, av.w};
      const float b_[4] = {bv.x, bv.y, bv.z, bv.w};
      #pragma unroll
      for (int i = 0; i < 4; ++i)
        #pragma unroll
        for (int j = 0; j < 4; ++j)
          acc[i][j] = fmaf(a_[i], b_[j], acc[i][j]);
    }
    __syncthreads();
  }

  #pragma unroll
  for (int i = 0; i < 4; ++i) {
    const int r = row0 + ty * 4 + i;
    #pragma unroll
    for (int j = 0; j < 4; ++j) {
      const int c = col0 + tx * 4 + j;
      if (c < N) {
        float v = acc[i][j] + bias[c];
        v = fmaxf(v, 0.0f);
        C[(size_t)r * N + c] = v;
      }
    }
  }
}

// Zero the three cmax accumulator slots (deterministic per launch).
__global__ void init_kernel(unsigned int* c)
{
  if (threadIdx.x < 3) c[threadIdx.x] = 0u;
}

// Global max over elements of max(h^2, (h-1)^2); h >= 0 so float-as-uint
// atomicMax is order-preserving.
__global__ __launch_bounds__(256) void cmax_kernel(
    const float* __restrict__ H, int count, unsigned int* __restrict__ cmax)
{
  int idx = blockIdx.x * blockDim.x + threadIdx.x;
  const int stride = gridDim.x * blockDim.x;
  float m = 0.0f;
  for (int i = idx; i < count; i += stride) {
    const float h = H[i];
    const float c0 = h * h;
    const float hm = h - 1.0f;
    const float c1 = hm * hm;
    m = fmaxf(m, fmaxf(c0, c1));
  }
  #pragma unroll
  for (int off = 32; off; off >>= 1)
    m = fmaxf(m, __shfl_xor(m, off));
  if ((threadIdx.x & 63) == 0)
    atomicMax(cmax, __float_as_uint(m));
}

// One wave per row. Exact 2-anchor Sinkhorn reduction:
//   R_i = exp((2h_i - 1)/(eps*cmax)), iterate t <- 0.25*A/B 49 times (t0=1),
//   A = sum 1/(1+t R), B = sum R/(1+t R); mask_i = K/(1+t R_i)/A.
// Output = h * (s*mask + (1-s)).
__global__ __launch_bounds__(64) void sinkhorn_kernel(
    const float* __restrict__ H, float* __restrict__ Out,
    const float* __restrict__ cmaxp, const int* __restrict__ sparse, int n)
{
  const int row  = blockIdx.x;
  const int lane = threadIdx.x;
  const float cmax = cmaxp[0];
  const float s = (float)sparse[0];
  const float inv = 1.0f / (0.1f * cmax);

  float h[8], R[8];
  bool val[8];
  const float* Hr = H + (size_t)row * n;
  #pragma unroll
  for (int j = 0; j < 8; ++j) {
    const int i = lane + 64 * j;
    val[j] = (i < n);
    h[j] = val[j] ? Hr[i] : 0.0f;
    R[j] = expf((2.0f * h[j] - 1.0f) * inv);
  }

  float t = 1.0f;
  float A = 0.0f, B = 0.0f;
  for (int it = 0; it < 50; ++it) {
    A = 0.0f; B = 0.0f;
    #pragma unroll
    for (int j = 0; j < 8; ++j) {
      if (val[j]) {
        const float w = 1.0f / (1.0f + t * R[j]);
        A += w;
        B += R[j] * w;
      }
    }
    #pragma unroll
    for (int off = 32; off; off >>= 1) {
      A += __shfl_xor(A, off);
      B += __shfl_xor(B, off);
    }
    if (it < 49) t = 0.25f * A / B;
  }

  const float kA = 400.0f / A;
  float* Or = Out + (size_t)row * n;
  #pragma unroll
  for (int j = 0; j < 8; ++j) {
    const int i = lane + 64 * j;
    if (val[j]) {
      const float mask = kA / (1.0f + t * R[j]);
      Or[i] = h[j] * (s * mask + (1.0f - s));
    }
  }
}

// Final [4096x500] @ [500x10] + b4. One wave per row.
__global__ __launch_bounds__(64) void gemm4_kernel(
    const float* __restrict__ H, const float* __restrict__ W,
    const float* __restrict__ b, float* __restrict__ out)
{
  const int row = blockIdx.x;
  const int lane = threadIdx.x;
  float acc[10];
  #pragma unroll
  for (int o = 0; o < 10; ++o) acc[o] = 0.0f;

  const float* Hr = H + (size_t)row * 500;
  #pragma unroll
  for (int j = 0; j < 8; ++j) {
    const int kidx = lane + 64 * j;
    if (kidx < 500) {
      const float hv = Hr[kidx];
      const float* Wr = W + (size_t)kidx * 10;
      #pragma unroll
      for (int o = 0; o < 10; ++o)
        acc[o] = fmaf(hv, Wr[o], acc[o]);
    }
  }
  #pragma unroll
  for (int o = 0; o < 10; ++o) {
    #pragma unroll
    for (int off = 32; off; off >>= 1)
      acc[o] += __shfl_xor(acc[o], off);
  }
  if (lane == 0) {
    #pragma unroll
    for (int o = 0; o < 10; ++o)
      out[(size_t)row * 10 + o] = acc[o] + b[o];
  }
}

extern "C" void kernel_launch(void* const* d_in, const int* in_sizes, int n_in,
                              void* d_out, int out_size, void* d_ws, size_t ws_size,
                              hipStream_t stream)
{
  const float* x  = (const float*)d_in[0];
  const float* W1 = (const float*)d_in[1];
  const float* b1 = (const float*)d_in[2];
  const float* W2 = (const float*)d_in[3];
  const float* b2 = (const float*)d_in[4];
  const float* W3 = (const float*)d_in[5];
  const float* b3 = (const float*)d_in[6];
  const float* W4 = (const float*)d_in[7];
  const float* b4 = (const float*)d_in[8];
  const int* sparse = (const int*)d_in[9];

  float* out = (float*)d_out;
  char* ws = (char*)d_ws;
  unsigned int* cmax = (unsigned int*)ws;
  float* buf0 = (float*)(ws + 4096);
  float* buf1 = (float*)(ws + 4096 + (size_t)4096 * 500 * 4);

  const int M = 4096, N = 500;
  const dim3 gg(8, 64), gb(256);

  init_kernel<<<1, 64, 0, stream>>>(cmax);

  // layer 1
  gemm_bias_relu<<<gg, gb, 0, stream>>>(x, W1, b1, buf0, M, N, 1024);
  cmax_kernel<<<dim3(512), dim3(256), 0, stream>>>(buf0, M * N, cmax + 0);
  sinkhorn_kernel<<<dim3(M), dim3(64), 0, stream>>>(buf0, buf1, (const float*)(cmax + 0), sparse, N);

  // layer 2
  gemm_bias_relu<<<gg, gb, 0, stream>>>(buf1, W2, b2, buf0, M, N, 500);
  cmax_kernel<<<dim3(512), dim3(256), 0, stream>>>(buf0, M * N, cmax + 1);
  sinkhorn_kernel<<<dim3(M), dim3(64), 0, stream>>>(buf0, buf1, (const float*)(cmax + 1), sparse, N);

  // layer 3
  gemm_bias_relu<<<gg, gb, 0, stream>>>(buf1, W3, b3, buf0, M, N, 500);
  cmax_kernel<<<dim3(512), dim3(256), 0, stream>>>(buf0, M * N, cmax + 2);
  sinkhorn_kernel<<<dim3(M), dim3(64), 0, stream>>>(buf0, buf1, (const float*)(cmax + 2), sparse, N);

  // output layer
  gemm4_kernel<<<dim3(M), dim3(64), 0, stream>>>(buf1, W4, b4, out);
}